// Round 8
// baseline (61.210 us; speedup 1.0000x reference)
//
#include <hip/hip_runtime.h>
#include <math.h>

// Problem: S=4096, B=16, H=1024
//   energies[b,s] = hidden[b,:] . (W @ enc[s,b,:] + b_attn)
//   out[b,0,s]    = softmax_s(energies[b,s])
// Reassociated: energies[b,s] = v[b,:] . enc[s,b,:] (+ const_b, which cancels
// under softmax shift-invariance), v = hidden @ W.  b_attn never read.
//
// History: coop fusion refuted (R4, scratch spill). nontemporal refuted (R2).
// B @ 8 waves/SIMD refuted (R6). B strided-reg (R5) == B contiguous-LDS (R7)
// == ~40-44us ~= 6.4 TB/s = device read ceiling -> B is at its floor.
// R8: single-dispatch GEMV (in-block k-split + LDS reduce, no ws traffic),
// 3 dispatches total: A ~2.5us, B ~40-44us, C ~3us.

#define SS 4096
#define BB 16
#define HH 1024

#define BNB 512        // kernel B: blocks (2 per CU)
#define BNT 512        // kernel B: threads per block (8 waves)
#define NGRP (SS * BB / 32)   // 2048 groups of 32 consecutive pairs
#define TILES (NGRP / BNB)    // 4 groups per block

typedef float f4 __attribute__((ext_vector_type(4)));

// ---- A: v[b,h] = sum_k hidden[b,k] * W[k,h]  (ONE dispatch) ---------------
// 256 blocks x 256 threads. Block -> (b = bid>>4, h-chunk of 64). The 4 waves
// split k 4x256: wave kc accumulates over k in [kc*256, kc*256+256). W reads:
// 64 lanes read 64 consecutive h (256 B, coalesced); hidden[b,k] is
// wave-uniform. Partials reduced through 1 KB of LDS, lane-coalesced.
__global__ void __launch_bounds__(256)
gemv_kernel(const float* __restrict__ hidden,
            const float* __restrict__ W,
            float* __restrict__ v) {
    int b  = blockIdx.x >> 4;
    int o  = threadIdx.x & 63;
    int kc = threadIdx.x >> 6;                  // wave index = k-chunk
    int h  = ((blockIdx.x & 15) << 6) | o;
    const float* hrow = hidden + b * HH + kc * 256;
    const float* Wp   = W + (size_t)(kc * 256) * HH + h;
    float a0 = 0.f, a1 = 0.f, a2 = 0.f, a3 = 0.f;
    #pragma unroll 4
    for (int k = 0; k < 256; k += 4) {
        a0 += hrow[k + 0] * Wp[(k + 0) * HH];
        a1 += hrow[k + 1] * Wp[(k + 1) * HH];
        a2 += hrow[k + 2] * Wp[(k + 2) * HH];
        a3 += hrow[k + 3] * Wp[(k + 3) * HH];
    }
    __shared__ float red[256];
    red[threadIdx.x] = (a0 + a1) + (a2 + a3);
    __syncthreads();
    if (threadIdx.x < 64) {
        v[b * HH + h] = red[o] + red[64 + o] + red[128 + o] + red[192 + o];
    }
}

// ---- B: energies[b,s] = v[b,:] . enc[s,b,:]  (persistent + contiguous) ----
// (unchanged from R7 — at the 6.4 TB/s read ceiling)
// 512 blocks x 512 threads, 2 blocks/CU (LDS 64 KB/block). Each block stages
// the whole v (64 KB) into LDS once, then sweeps TILES=4 groups of 32
// CONSECUTIVE pairs p = s*16+b; wave i takes pairs p0=g*32+i*4..+3, i.e. one
// contiguous 16 KB span of enc per wave per tile. vv comes from LDS per pair
// (conflict-free consecutive-lane ds_read_b128). Butterfly-reduce, lane0
// writes 4 floats.
__global__ void __launch_bounds__(BNT, 4)
energies_kernel(const float* __restrict__ enc,
                const float* __restrict__ v,
                float* __restrict__ out) {
    __shared__ f4 vlds[BB * HH / 4];        // 4096 f4 = 64 KB
    int tid = threadIdx.x;
    const f4* vg = (const f4*)v;
    #pragma unroll
    for (int it = 0; it < (BB * HH / 4) / BNT; ++it)   // 8 iters
        vlds[it * BNT + tid] = vg[it * BNT + tid];
    __syncthreads();

    int lane = tid & 63;
    int wi   = tid >> 6;                    // wave in block, 0..7
    for (int t = 0; t < TILES; ++t) {
        int g  = t * BNB + blockIdx.x;      // group 0..2047
        int p0 = g * 32 + wi * 4;           // first of 4 consecutive pairs
        float acc[4];
        #pragma unroll
        for (int j = 0; j < 4; ++j) {
            int p = p0 + j;
            int b = p & (BB - 1);
            const f4* e4 = (const f4*)(enc + (size_t)p * HH);
            f4 a0 = e4[0 * 64 + lane];
            f4 a1 = e4[1 * 64 + lane];
            f4 a2 = e4[2 * 64 + lane];
            f4 a3 = e4[3 * 64 + lane];
            f4 w0 = vlds[b * 256 + 0 * 64 + lane];
            f4 w1 = vlds[b * 256 + 1 * 64 + lane];
            f4 w2 = vlds[b * 256 + 2 * 64 + lane];
            f4 w3 = vlds[b * 256 + 3 * 64 + lane];
            f4 pr = a0 * w0 + a1 * w1 + a2 * w2 + a3 * w3;
            acc[j] = (pr.x + pr.y) + (pr.z + pr.w);
        }
        #pragma unroll
        for (int j = 0; j < 4; ++j) {
            #pragma unroll
            for (int off = 32; off; off >>= 1)
                acc[j] += __shfl_xor(acc[j], off, 64);
        }
        if (lane == 0) {
            #pragma unroll
            for (int j = 0; j < 4; ++j) {
                int p = p0 + j;
                out[(p & (BB - 1)) * SS + (p >> 4)] = acc[j];
            }
        }
    }
}

// ---- C: in-place softmax over s, one 256-thread block per b (unchanged) ---
__global__ void __launch_bounds__(256)
softmax_kernel(float* __restrict__ out) {
    int b = blockIdx.x;
    float* row = out + b * SS;
    int t = threadIdx.x;                 // 16 values per thread
    float vals[16];
    float m = -INFINITY;
    #pragma unroll
    for (int i = 0; i < 16; ++i) {
        vals[i] = row[t + i * 256];
        m = fmaxf(m, vals[i]);
    }
    #pragma unroll
    for (int off = 32; off; off >>= 1) m = fmaxf(m, __shfl_xor(m, off, 64));
    __shared__ float redm[4];
    __shared__ float reds[4];
    int wid = t >> 6;
    if ((t & 63) == 0) redm[wid] = m;
    __syncthreads();
    m = fmaxf(fmaxf(redm[0], redm[1]), fmaxf(redm[2], redm[3]));

    float sum = 0.f;
    #pragma unroll
    for (int i = 0; i < 16; ++i) {
        vals[i] = expf(vals[i] - m);
        sum += vals[i];
    }
    #pragma unroll
    for (int off = 32; off; off >>= 1) sum += __shfl_xor(sum, off, 64);
    if ((t & 63) == 0) reds[wid] = sum;
    __syncthreads();
    sum = reds[0] + reds[1] + reds[2] + reds[3];
    float inv = 1.0f / sum;
    #pragma unroll
    for (int i = 0; i < 16; ++i) row[t + i * 256] = vals[i] * inv;
}

extern "C" void kernel_launch(void* const* d_in, const int* in_sizes, int n_in,
                              void* d_out, int out_size, void* d_ws, size_t ws_size,
                              hipStream_t stream) {
    const float* hidden = (const float*)d_in[0];   // [1,B,H]
    const float* enc    = (const float*)d_in[1];   // [S,B,H]
    const float* W      = (const float*)d_in[2];   // [H,H]
    // d_in[3] = b_attn: cancels in softmax (and is zero in setup_inputs)
    float* out = (float*)d_out;                    // [B,1,S]
    float* v   = (float*)d_ws;                     // B*H floats = 64 KB

    hipLaunchKernelGGL(gemv_kernel, dim3(BB * 16), dim3(256), 0, stream,
                       hidden, W, v);
    hipLaunchKernelGGL(energies_kernel, dim3(BNB), dim3(BNT), 0, stream,
                       enc, v, out);
    hipLaunchKernelGGL(softmax_kernel, dim3(BB), dim3(256), 0, stream, out);
}